// Round 10
// baseline (696.137 us; speedup 1.0000x reference)
//
#include <hip/hip_runtime.h>
#include <hip/hip_bf16.h>

// Problem constants
#define BB 64
#define SS 512
#define DD 128
#define NROW (BB * SS)          // 32768
#define SZ ((size_t)NROW * DD)  // 4,194,304 elems per [B,S,128] slice

#define LOG2E 1.4426950408889634f
#define QSCALE (0.125f * LOG2E)

typedef __attribute__((ext_vector_type(8))) short short8;
typedef __attribute__((ext_vector_type(4))) float f32x4;

// WB (converted-weight buffer) element offsets, all bf16:
#define WB_P1 0          // fc1W^T [128][320] (K=300 pad 320)
#define WB_P2 40960      // fc2W^T [128][64]  (K=35 pad 64)
#define WB_P3 49152      // fc3W^T [128][96]  (K=74 pad 96)
#define WB_QKVD 61440    // [4 op][6 u][128 n][128 k]  (op0=Wq prescaled by QSCALE)
#define WB_WIH 454656    // [6 rec][384 n][128 k]  (prescaled by log2e/2log2e)
#define WB_WHH 749568    // [6 rec][384 n][128 k]  (prescaled by log2e/2log2e)
#define WB_TOTAL 1044480

__device__ __forceinline__ float frcp_(float x) { return __builtin_amdgcn_rcpf(x); }
__device__ __forceinline__ float fexp2_(float x) { return __builtin_amdgcn_exp2f(x); }
__device__ __forceinline__ float b2f(unsigned short u) {
  union { unsigned int i; float f; } x; x.i = ((unsigned int)u) << 16; return x.f;
}
__device__ __forceinline__ unsigned short f2b(float f) {
  __hip_bfloat16 b = __float2bfloat16(f);
  return *reinterpret_cast<unsigned short*>(&b);
}
__device__ __forceinline__ unsigned short f2b_trunc(float f) {
  union { float f; unsigned int i; } x; x.f = f; return (unsigned short)(x.i >> 16);
}

// ---------------------------------------------------------------------------
// Weight prep.  Wq prescaled by QSCALE; GRU weights prescaled by log2e (r,z)
// / 2log2e (n).  gbihs = scale*(gbih + gbhh) for r,z gates; for n gate
// gbihs = scale*gbih only (bhh_n carried by gru kernel's cbhn accumulator).
// ---------------------------------------------------------------------------
__global__ __launch_bounds__(256) void prep_kernel(
    const float* __restrict__ fc1W, const float* __restrict__ fc2W,
    const float* __restrict__ fc3W, const float* __restrict__ Wq,
    const float* __restrict__ Wk, const float* __restrict__ Wv,
    const float* __restrict__ Wd, const float* __restrict__ gWih,
    const float* __restrict__ gWhh, const float* __restrict__ gbih,
    const float* __restrict__ gbhh, const float* __restrict__ bq,
    unsigned short* __restrict__ WB, float* __restrict__ gbihs,
    float* __restrict__ bqs) {
  for (int idx = blockIdx.x * 256 + threadIdx.x; idx < WB_TOTAL;
       idx += gridDim.x * 256) {
    float v;
    if (idx < WB_P2) {
      int n = idx / 320, k = idx % 320;
      v = (k < 300) ? fc1W[k * 128 + n] : 0.f;
    } else if (idx < WB_P3) {
      int r = idx - WB_P2; int n = r >> 6, k = r & 63;
      v = (k < 35) ? fc2W[k * 128 + n] : 0.f;
    } else if (idx < WB_QKVD) {
      int r = idx - WB_P3; int n = r / 96, k = r % 96;
      v = (k < 74) ? fc3W[k * 128 + n] : 0.f;
    } else if (idx < WB_WIH) {
      int r = idx - WB_QKVD;
      int op = r / 98304; int r2 = r % 98304;
      int u = r2 >> 14; int r3 = r2 & 16383;
      int n = r3 >> 7, k = r3 & 127;
      const float* src = (op == 0) ? Wq : (op == 1) ? Wk : (op == 2) ? Wv : Wd;
      v = src[u * 16384 + k * 128 + n];
      if (op == 0) v *= QSCALE;
    } else if (idx < WB_WHH) {
      int r = idx - WB_WIH;
      int r3 = r % 49152;  // within rec: [384 n][128 k]
      int gate = (r3 >> 7) >> 7;
      v = gWih[r] * (gate < 2 ? LOG2E : 2.f * LOG2E);
    } else {
      int r = idx - WB_WHH;
      int r3 = r % 49152;
      int gate = (r3 >> 7) >> 7;
      v = gWhh[r] * (gate < 2 ? LOG2E : 2.f * LOG2E);
    }
    WB[idx] = f2b(v);
  }
  for (int idx = blockIdx.x * 256 + threadIdx.x; idx < 6 * 384;
       idx += gridDim.x * 256) {
    int gate = (idx % 384) >> 7;
    float v = gbih[idx] + (gate < 2 ? gbhh[idx] : 0.f);
    gbihs[idx] = v * (gate < 2 ? LOG2E : 2.f * LOG2E);
  }
  for (int idx = blockIdx.x * 256 + threadIdx.x; idx < 6 * 128;
       idx += gridDim.x * 256) {
    bqs[idx] = bq[idx] * QSCALE;
  }
}

// ---------------------------------------------------------------------------
// GArg: shared by all gemm kernels.  For gemm_k128g, entries are grouped in
// blocks of `gw` sharing one A tile; abf of a group's FIRST entry = number of
// live entries (nw).  For gemm_proj, abf=1 marks 16B-aligned f32 A rows.
// For gemm_dln: cbf = accumulate flag; g2/b2 = LN gamma/beta (pre-offset).
// ---------------------------------------------------------------------------
struct GArg {
  const void* A; const unsigned short* W; const float* bias; void* C;
  int Ka, Kp, abf, cbf, cs; float* vsum;
  const float* g2; const float* b2;
};
struct GArgs { GArg g[18]; int gw; int pad_; };

#define CST 5120  // chunk stride in shorts (128 rows * 40)

// ---------------------------------------------------------------------------
// gemm_proj: staged whole-tile path for the f32-input projections.
// Stages of up to 96 k-cols (3 chunks, 60KB LDS): {stage A(f32->bf16,
// float4-vectorized when abf) + W -> barrier -> nc x 16 MFMA -> barrier}.
// (R8: -14us vs per-32 loop.)
// ---------------------------------------------------------------------------
__global__ __launch_bounds__(256) void gemm_proj(GArgs args) {
  const GArg ga = args.g[blockIdx.z];
  __shared__ unsigned short As[3 * CST];
  __shared__ unsigned short Ws[3 * CST];
  const int t = threadIdx.x;
  const int lane = t & 63, q = lane >> 4, lm = lane & 15;
  const int w = t >> 6, wm = w >> 1, wn = w & 1;
  const int m0 = blockIdx.x * 128;
  const int row = t >> 1, half = t & 1;

  f32x4 acc[4][4];
#pragma unroll
  for (int i = 0; i < 4; ++i)
#pragma unroll
    for (int j = 0; j < 4; ++j) acc[i][j] = (f32x4){0.f, 0.f, 0.f, 0.f};

  const float* Ab = (const float*)ga.A + (size_t)(m0 + row) * ga.Ka;
  const unsigned short* Wb = ga.W + (size_t)row * ga.Kp;

  for (int k0 = 0; k0 < ga.Kp; k0 += 96) {
    const int SW = (ga.Kp - k0 < 96) ? (ga.Kp - k0) : 96;  // 96/64/32, mult 32
    const int hw = SW >> 1;                                // 48/32/16 cols/thread
    const int cbase = half * hw;
    if (k0) __syncthreads();  // prior stage fully consumed

    if (ga.abf) {
      // 16B-aligned rows, Ka%4==0: whole-granule masking, float4 loads.
#pragma unroll 4
      for (int j = 0; j < hw; j += 4) {
        const int cg = k0 + cbase + j;
        float4 v = {0.f, 0.f, 0.f, 0.f};
        if (cg + 4 <= ga.Ka) v = *reinterpret_cast<const float4*>(Ab + cg);
        const int cc = cbase + j, lc = cc >> 5, co = cc & 31;
        unsigned short tp[4] = {f2b(v.x), f2b(v.y), f2b(v.z), f2b(v.w)};
        *reinterpret_cast<unsigned long long*>(&As[lc * CST + row * 40 + co]) =
            *reinterpret_cast<unsigned long long*>(tp);
      }
    } else {
      // misaligned rows (vis/aud): scalar masked loads (single-stage slices).
#pragma unroll 4
      for (int j = 0; j < hw; j += 4) {
        const int cg = k0 + cbase + j;
        unsigned short tp[4];
#pragma unroll
        for (int e = 0; e < 4; ++e)
          tp[e] = (cg + e < ga.Ka) ? f2b(Ab[cg + e]) : (unsigned short)0;
        const int cc = cbase + j, lc = cc >> 5, co = cc & 31;
        *reinterpret_cast<unsigned long long*>(&As[lc * CST + row * 40 + co]) =
            *reinterpret_cast<unsigned long long*>(tp);
      }
    }
    // W stage: bf16, rows are 16B-multiples (Kp mult of 32).
#pragma unroll 2
    for (int j = 0; j < hw; j += 8) {
      const int cg = k0 + cbase + j;
      short8 v = *reinterpret_cast<const short8*>(Wb + cg);
      const int cc = cbase + j, lc = cc >> 5, co = cc & 31;
      *reinterpret_cast<short8*>(&Ws[lc * CST + row * 40 + co]) = v;
    }
    __syncthreads();

    const int nc = SW >> 5;
    for (int c = 0; c < nc; ++c) {
      short8 af[4], bfv[4];
#pragma unroll
      for (int mi = 0; mi < 4; ++mi)
        af[mi] = *reinterpret_cast<const short8*>(
            &As[c * CST + (wm * 64 + mi * 16 + lm) * 40 + q * 8]);
#pragma unroll
      for (int ni = 0; ni < 4; ++ni)
        bfv[ni] = *reinterpret_cast<const short8*>(
            &Ws[c * CST + (wn * 64 + ni * 16 + lm) * 40 + q * 8]);
#pragma unroll
      for (int mi = 0; mi < 4; ++mi)
#pragma unroll
        for (int ni = 0; ni < 4; ++ni)
          acc[mi][ni] = __builtin_amdgcn_mfma_f32_16x16x32_bf16(
              af[mi], bfv[ni], acc[mi][ni], 0, 0, 0);
    }
  }

#pragma unroll
  for (int ni = 0; ni < 4; ++ni) {
    const int colg = wn * 64 + ni * 16 + lm;
    const float bv = ga.bias[colg];
#pragma unroll
    for (int mi = 0; mi < 4; ++mi) {
      const int rg = m0 + wm * 64 + mi * 16 + q * 4;
#pragma unroll
      for (int r = 0; r < 4; ++r) {
        float v = acc[mi][ni][r] + bv;
        ((unsigned short*)ga.C)[(size_t)(rg + r) * ga.cs + colg] = f2b(v);
      }
    }
  }
}

// ---------------------------------------------------------------------------
// gemm_k128g: grouped whole-tile path for bf16 A, K==128 slices.
// grid z = A-group.  Stage the group's shared 128x128 A tile ONCE, then loop
// over its nw W-tiles: {stage W -> barrier -> 64 MFMA -> epilogue -> barrier}.
// (R7: -23us vs per-z launches.)
// ---------------------------------------------------------------------------
__global__ __launch_bounds__(256) void gemm_k128g(GArgs args) {
  const int base = blockIdx.z * args.gw;
  const int nw = args.g[base].abf;
  __shared__ unsigned short As4[4 * CST];
  __shared__ unsigned short Ws4[4 * CST];
  const int t = threadIdx.x;
  const int lane = t & 63, q = lane >> 4, lm = lane & 15;
  const int w = t >> 6, wm = w >> 1, wn = w & 1;
  const int m0 = blockIdx.x * 128;

  // staging geometry: thread covers rows (t>>4)+16p, col octet (t&15)*8
  const int srow = t >> 4, scol = (t & 15) * 8;
  const int sc = scol >> 5, soff = scol & 31;

  {  // stage shared A tile once
    const unsigned short* Ab =
        (const unsigned short*)args.g[base].A + (size_t)(m0 + srow) * 128 + scol;
#pragma unroll
    for (int p = 0; p < 8; ++p) {
      short8 av = *reinterpret_cast<const short8*>(Ab + (size_t)p * 16 * 128);
      *reinterpret_cast<short8*>(&As4[sc * CST + (srow + p * 16) * 40 + soff]) = av;
    }
  }

  for (int i = 0; i < nw; ++i) {
    const GArg ge = args.g[base + i];
    if (i) __syncthreads();  // all waves done reading Ws4 of entry i-1
    {
      const unsigned short* Wg = ge.W + (size_t)srow * 128 + scol;
#pragma unroll
      for (int p = 0; p < 8; ++p) {
        short8 wv = *reinterpret_cast<const short8*>(Wg + (size_t)p * 16 * 128);
        *reinterpret_cast<short8*>(&Ws4[sc * CST + (srow + p * 16) * 40 + soff]) = wv;
      }
    }
    __syncthreads();

    f32x4 acc[4][4];
#pragma unroll
    for (int ii = 0; ii < 4; ++ii)
#pragma unroll
      for (int jj = 0; jj < 4; ++jj) acc[ii][jj] = (f32x4){0.f, 0.f, 0.f, 0.f};

#pragma unroll
    for (int c = 0; c < 4; ++c) {
      short8 af[4], bfv[4];
#pragma unroll
      for (int mi = 0; mi < 4; ++mi)
        af[mi] = *reinterpret_cast<const short8*>(
            &As4[c * CST + (wm * 64 + mi * 16 + lm) * 40 + q * 8]);
#pragma unroll
      for (int ni = 0; ni < 4; ++ni)
        bfv[ni] = *reinterpret_cast<const short8*>(
            &Ws4[c * CST + (wn * 64 + ni * 16 + lm) * 40 + q * 8]);
#pragma unroll
      for (int mi = 0; mi < 4; ++mi)
#pragma unroll
        for (int ni = 0; ni < 4; ++ni)
          acc[mi][ni] = __builtin_amdgcn_mfma_f32_16x16x32_bf16(
              af[mi], bfv[ni], acc[mi][ni], 0, 0, 0);
    }

#pragma unroll
    for (int ni = 0; ni < 4; ++ni) {
      const int colg = wn * 64 + ni * 16 + lm;
      const float bv = ge.bias[colg];
#pragma unroll
      for (int mi = 0; mi < 4; ++mi) {
        const int rg = m0 + wm * 64 + mi * 16 + q * 4;
#pragma unroll
        for (int r = 0; r < 4; ++r) {
          float v = acc[mi][ni][r] + bv;
          ((unsigned short*)ge.C)[(size_t)(rg + r) * ge.cs + colg] = f2b(v);
        }
      }
    }
    if (ge.vsum) {
      float* vp = ge.vsum + (size_t)(m0 >> 9) * 128;
#pragma unroll
      for (int ni = 0; ni < 4; ++ni) {
        const int colg = wn * 64 + ni * 16 + lm;
        float s = 16.f * ge.bias[colg];
#pragma unroll
        for (int mi = 0; mi < 4; ++mi)
#pragma unroll
          for (int r = 0; r < 4; ++r) s += acc[mi][ni][r];
        atomicAdd(&vp[colg], s);
      }
    }
  }
}

// ---------------------------------------------------------------------------
// gemm_dln: dense Wd GEMM with FUSED LayerNorm epilogue (replaces the old
// DOUT round trip + ln_pair kernel: -120MB HBM traffic + 1 launch).
// Each block computes a full 128x128 tile = complete LN rows.  Row stats:
// per-thread partials over 4 ni-cols -> shfl_xor over 16 lm-lanes ->
// cross-wave (wn) combine via a 2KB LB buffer aliased into dead As4 LDS
// (keeps 80KB -> 2 blocks/CU).  cbf=0: C = f2b(0.5*LN); cbf=1: C += ...
// (two stream-ordered launches for the unit pairs).
// ---------------------------------------------------------------------------
__global__ __launch_bounds__(256) void gemm_dln(GArgs args) {
  const GArg ga = args.g[blockIdx.z];
  __shared__ unsigned short As4[4 * CST];
  __shared__ unsigned short Ws4[4 * CST];
  const int t = threadIdx.x;
  const int lane = t & 63, q = lane >> 4, lm = lane & 15;
  const int w = t >> 6, wm = w >> 1, wn = w & 1;
  const int m0 = blockIdx.x * 128;

  const int srow = t >> 4, scol = (t & 15) * 8;
  const int sc = scol >> 5, soff = scol & 31;
  {
    const unsigned short* Ab =
        (const unsigned short*)ga.A + (size_t)(m0 + srow) * 128 + scol;
    const unsigned short* Wg = ga.W + (size_t)srow * 128 + scol;
#pragma unroll
    for (int p = 0; p < 8; ++p) {
      short8 av = *reinterpret_cast<const short8*>(Ab + (size_t)p * 16 * 128);
      short8 wv = *reinterpret_cast<const short8*>(Wg + (size_t)p * 16 * 128);
      *reinterpret_cast<short8*>(&As4[sc * CST + (srow + p * 16) * 40 + soff]) = av;
      *reinterpret_cast<short8*>(&Ws4[sc * CST + (srow + p * 16) * 40 + soff]) = wv;
    }
  }
  __syncthreads();

  f32x4 acc[4][4];
#pragma unroll
  for (int i = 0; i < 4; ++i)
#pragma unroll
    for (int j = 0; j < 4; ++j) acc[i][j] = (f32x4){0.f, 0.f, 0.f, 0.f};

#pragma unroll
  for (int c = 0; c < 4; ++c) {
    short8 af[4], bfv[4];
#pragma unroll
    for (int mi = 0; mi < 4; ++mi)
      af[mi] = *reinterpret_cast<const short8*>(
          &As4[c * CST + (wm * 64 + mi * 16 + lm) * 40 + q * 8]);
#pragma unroll
    for (int ni = 0; ni < 4; ++ni)
      bfv[ni] = *reinterpret_cast<const short8*>(
          &Ws4[c * CST + (wn * 64 + ni * 16 + lm) * 40 + q * 8]);
#pragma unroll
    for (int mi = 0; mi < 4; ++mi)
#pragma unroll
      for (int ni = 0; ni < 4; ++ni)
        acc[mi][ni] = __builtin_amdgcn_mfma_f32_16x16x32_bf16(
            af[mi], bfv[ni], acc[mi][ni], 0, 0, 0);
  }

  // ---- fused LN epilogue ----
  float bv[4], gg[4], bb[4];
#pragma unroll
  for (int ni = 0; ni < 4; ++ni) {
    const int colg = wn * 64 + ni * 16 + lm;
    bv[ni] = ga.bias[colg];
    gg[ni] = ga.g2[colg];
    bb[ni] = ga.b2[colg];
  }
  float s[4][4], sq[4][4];  // [mi][r]
#pragma unroll
  for (int mi = 0; mi < 4; ++mi)
#pragma unroll
    for (int r = 0; r < 4; ++r) {
      float ss = 0.f, qq = 0.f;
#pragma unroll
      for (int ni = 0; ni < 4; ++ni) {
        float val = acc[mi][ni][r] + bv[ni];
        ss += val; qq += val * val;
      }
      s[mi][r] = ss; sq[mi][r] = qq;
    }
#pragma unroll
  for (int m = 1; m < 16; m <<= 1)
#pragma unroll
    for (int mi = 0; mi < 4; ++mi)
#pragma unroll
      for (int r = 0; r < 4; ++r) {
        s[mi][r] += __shfl_xor(s[mi][r], m);
        sq[mi][r] += __shfl_xor(sq[mi][r], m);
      }
  // cross-wave (wn) combine through LB aliased into As4 (dead after MFMA).
  float2* LB = reinterpret_cast<float2*>(As4);  // [wm*64+row][wn]
  __syncthreads();  // all MFMA LDS reads done before overwriting As4
  if (lm == 0) {
#pragma unroll
    for (int mi = 0; mi < 4; ++mi)
#pragma unroll
      for (int r = 0; r < 4; ++r) {
        float2 p; p.x = s[mi][r]; p.y = sq[mi][r];
        LB[(wm * 64 + mi * 16 + q * 4 + r) * 2 + wn] = p;
      }
  }
  __syncthreads();

#pragma unroll
  for (int mi = 0; mi < 4; ++mi)
#pragma unroll
    for (int r = 0; r < 4; ++r) {
      float2 oth = LB[(wm * 64 + mi * 16 + q * 4 + r) * 2 + (wn ^ 1)];
      const float stot = s[mi][r] + oth.x;
      const float sqt = sq[mi][r] + oth.y;
      const float mean = stot * (1.f / 128.f);
      const float var = sqt * (1.f / 128.f) - mean * mean;
      const float rs = rsqrtf(var + 1e-5f);
      const int rg = m0 + wm * 64 + mi * 16 + q * 4 + r;
      unsigned short* cp = (unsigned short*)ga.C + (size_t)rg * 128;
#pragma unroll
      for (int ni = 0; ni < 4; ++ni) {
        const int colg = wn * 64 + ni * 16 + lm;
        float val = acc[mi][ni][r] + bv[ni];
        float o = 0.5f * ((val - mean) * rs * gg[ni] + bb[ni]);
        if (ga.cbf) o += b2f(cp[colg]);
        cp[colg] = f2b(o);
      }
    }
}

// ---------------------------------------------------------------------------
// MFMA attention v2 (probs = 1 - softmax): ctx = Vsum - softmax(QK^T/8) @ V.
// grid = (2 q-halves, 128 = b*2+h, 3 units), block = 256 (4 waves).
// (round-4 version verbatim; round-5's swapped-PV/SB variant regressed.)
// ---------------------------------------------------------------------------
__global__ __launch_bounds__(256) void attn2(
    const unsigned short* __restrict__ QKV, const float* __restrict__ VS,
    unsigned short* __restrict__ CTX) {
  __shared__ unsigned short Vt[64 * 72];       // [d][k ^ (d&56)]
  __shared__ unsigned short Pt[4][16 * 72];    // per-wave [q][k]
  const int t = threadIdx.x;
  const int w = t >> 6, lane = t & 63, quad = lane >> 4, lm = lane & 15;
  const int z = blockIdx.z;
  const int bh = blockIdx.y, b = bh >> 1, h = bh & 1;
  const int qbase = blockIdx.x * 256;

  const unsigned short* Qg = QKV + (size_t)(z * 3 + 0) * SZ;
  const unsigned short* Kg = QKV + (size_t)(z * 3 + 1) * SZ;
  const unsigned short* Vg = QKV + (size_t)(z * 3 + 2) * SZ;

  short8 aq[4][2];
#pragma unroll
  for (int qt = 0; qt < 4; ++qt)
#pragma unroll
    for (int c = 0; c < 2; ++c)
      aq[qt][c] = *reinterpret_cast<const short8*>(
          Qg + ((size_t)(b * SS + qbase + qt * 64 + w * 16 + lm)) * DD +
          h * 64 + c * 32 + quad * 8);

  const f32x4 czero = {0.f, 0.f, 0.f, 0.f};
  f32x4 o[4][4];  // [qt][dt]
#pragma unroll
  for (int i = 0; i < 4; ++i)
#pragma unroll
    for (int j = 0; j < 4; ++j) o[i][j] = czero;
  float suml[4][4];  // [qt][r]
#pragma unroll
  for (int i = 0; i < 4; ++i)
#pragma unroll
    for (int j = 0; j < 4; ++j) suml[i][j] = 0.f;

  const int vk = t >> 3, vd0 = (t & 7) * 8;

  for (int kt = 0; kt < 8; ++kt) {
    const int k0 = kt * 64;
    __syncthreads();  // prior Vt fully consumed (bv regs read)
#pragma unroll
    for (int i = 0; i < 2; ++i) {
      const int k = vk + i * 32;
      short8 vv = *reinterpret_cast<const short8*>(
          Vg + ((size_t)(b * SS + k0 + k)) * DD + h * 64 + vd0);
#pragma unroll
      for (int j = 0; j < 8; ++j) {
        const int d = vd0 + j;
        Vt[d * 72 + (k ^ (d & 56))] = (unsigned short)vv[j];
      }
    }
    __syncthreads();

    short8 bk[4][2];
#pragma unroll
    for (int nt = 0; nt < 4; ++nt)
#pragma unroll
      for (int c = 0; c < 2; ++c)
        bk[nt][c] = *reinterpret_cast<const short8*>(
            Kg + ((size_t)(b * SS + k0 + nt * 16 + lm)) * DD + h * 64 +
            c * 32 + quad * 8);
    short8 bvv[4][2];
#pragma unroll
    for (int dt = 0; dt < 4; ++dt) {
      const int d = dt * 16 + lm;
#pragma unroll
      for (int c = 0; c < 2; ++c)
        bvv[dt][c] = *reinterpret_cast<const short8*>(
            &Vt[d * 72 + ((c * 32 + quad * 8) ^ (d & 56))]);
    }

#pragma unroll
    for (int qt = 0; qt < 4; ++qt) {
      f32x4 sacc[4];
#pragma unroll
      for (int nt = 0; nt < 4; ++nt)
        sacc[nt] = __builtin_amdgcn_mfma_f32_16x16x32_bf16(
            aq[qt][0], bk[nt][0], czero, 0, 0, 0);
#pragma unroll
      for (int nt = 0; nt < 4; ++nt)
        sacc[nt] = __builtin_amdgcn_mfma_f32_16x16x32_bf16(
            aq[qt][1], bk[nt][1], sacc[nt], 0, 0, 0);
#pragma unroll
      for (int nt = 0; nt < 4; ++nt) {
#pragma unroll
        for (int r = 0; r < 4; ++r) {
          float p = fexp2_(sacc[nt][r]);
          suml[qt][r] += p;
          Pt[w][(quad * 4 + r) * 72 + nt * 16 + lm] = f2b_trunc(p);
        }
      }
#pragma unroll
      for (int c = 0; c < 2; ++c) {
        short8 ap = *reinterpret_cast<const short8*>(
            &Pt[w][lm * 72 + c * 32 + quad * 8]);
#pragma unroll
        for (int dt = 0; dt < 4; ++dt)
          o[qt][dt] = __builtin_amdgcn_mfma_f32_16x16x32_bf16(
              ap, bvv[dt][c], o[qt][dt], 0, 0, 0);
      }
    }
  }
#pragma unroll
  for (int qt = 0; qt < 4; ++qt)
#pragma unroll
    for (int r = 0; r < 4; ++r) {
#pragma unroll
      for (int m = 1; m < 16; m <<= 1)
        suml[qt][r] += __shfl_xor(suml[qt][r], m);
    }
  const float* vsp = VS + (size_t)(z * BB + b) * DD + h * 64;
#pragma unroll
  for (int qt = 0; qt < 4; ++qt)
#pragma unroll
    for (int dt = 0; dt < 4; ++dt) {
      const int col = dt * 16 + lm;
      const float vs = vsp[col];
#pragma unroll
      for (int r = 0; r < 4; ++r) {
        const int row = qbase + qt * 64 + w * 16 + quad * 4 + r;
        CTX[(size_t)z * SZ + ((size_t)(b * SS + row)) * DD + h * 64 + col] =
            f2b(vs - o[qt][dt][r] * frcp_(suml[qt][r]));
      }
    }
}

// ---------------------------------------------------------------------------
// GRU v10 (confirmed best: 173-175us, stable across rounds).  Do not
// restructure (v11 regressed).  grid = (16 bg, 6 rec), block = 512 (8 waves).
// ---------------------------------------------------------------------------
#define AST 136

__global__ __launch_bounds__(512, 1) void gru8(
    const unsigned short* __restrict__ GXR, const unsigned short* __restrict__ WB,
    const float* __restrict__ gbhh, float* __restrict__ HS) {
  __shared__ unsigned short Abuf[2][16 * AST];
  const int rec = blockIdx.y, bg = blockIdx.x;
  const int dir = rec & 1;
  const int t = threadIdx.x;
  const int w = t >> 6, lane = t & 63, q = lane >> 4, lm = lane & 15;
  const int o = w * 16 + lm;
  const int b = bg * 4 + q;

  short8 Bh[3][4];
  const unsigned short* whh = WB + WB_WHH + (size_t)rec * 49152;
#pragma unroll
  for (int gate = 0; gate < 3; ++gate)
#pragma unroll
    for (int c = 0; c < 4; ++c)
      Bh[gate][c] = *reinterpret_cast<const short8*>(
          whh + (size_t)(gate * 128 + o) * 128 + c * 32 + q * 8);
  const float bhn = gbhh[rec * 384 + 256 + o] * (2.f * LOG2E);
  const f32x4 czero = {0.f, 0.f, 0.f, 0.f};
  const f32x4 cbhn = {bhn, 0.f, 0.f, 0.f};

  float h = 0.f, hsum = 0.f;
  for (int i = t; i < 2 * 16 * AST; i += 512)
    (&Abuf[0][0])[i] = 0;

  // gx: 3 ushort loads/step from GXR[rec][b*512 + tt][384] at cols g*128+o.
  const unsigned short* gx0 = GXR + (size_t)rec * 12582912 +
      ((size_t)b * 512 + (dir ? 511 : 0)) * 384 + o;
  const ptrdiff_t st = dir ? -384 : 384;

  unsigned short ring[4][3];
#pragma unroll
  for (int pp = 0; pp < 4; ++pp) {
    const unsigned short* gp = gx0 + (ptrdiff_t)pp * st;
#pragma unroll
    for (int j = 0; j < 3; ++j) ring[pp][j] = gp[j * 128];
  }
  const unsigned short* pf = gx0 + (ptrdiff_t)4 * st;  // prefetch ptr (s+4)
  __syncthreads();

#pragma unroll 4
  for (int s = 0; s < SS; ++s) {
    const int p = s & 1, slot = s & 3;
    const float gxr = b2f(ring[slot][0]);
    const float gxz = b2f(ring[slot][1]);
    const float gxn = b2f(ring[slot][2]);
#pragma unroll
    for (int j = 0; j < 3; ++j) ring[slot][j] = pf[j * 128];
    pf += (s < SS - 5) ? st : 0;  // uniform-cond pointer bump, stays in-bounds

    short8 ah0 = *reinterpret_cast<const short8*>(&Abuf[p][lm * AST + 0 + q * 8]);
    short8 ah1 = *reinterpret_cast<const short8*>(&Abuf[p][lm * AST + 32 + q * 8]);
    short8 ah2 = *reinterpret_cast<const short8*>(&Abuf[p][lm * AST + 64 + q * 8]);
    short8 ah3 = *reinterpret_cast<const short8*>(&Abuf[p][lm * AST + 96 + q * 8]);
    f32x4 r0 = __builtin_amdgcn_mfma_f32_16x16x32_bf16(ah0, Bh[0][0], czero, 0, 0, 0);
    f32x4 r1 = __builtin_amdgcn_mfma_f32_16x16x32_bf16(ah2, Bh[0][2], czero, 0, 0, 0);
    f32x4 z0 = __builtin_amdgcn_mfma_f32_16x16x32_bf16(ah0, Bh[1][0], czero, 0, 0, 0);
    f32x4 z1 = __builtin_amdgcn_mfma_f32_16x16x32_bf16(ah2, Bh[1][2], czero, 0, 0, 0);
    f32x4 n0 = __builtin_amdgcn_mfma_f32_16x16x32_bf16(ah0, Bh[2][0], cbhn, 0, 0, 0);
    f32x4 n1 = __builtin_amdgcn_mfma_f32_16x16x32_bf16(ah2, Bh[2][2], czero, 0, 0, 0);
    r0 = __builtin_amdgcn_mfma_f32_16x16x32_bf16(ah1, Bh[0][1], r0, 0, 0, 0);
    r1 = __builtin_amdgcn_mfma_f32_16x16x32_bf16(ah3, Bh[0][3], r1, 0, 0, 0);
    z0 = __builtin_amdgcn_mfma_f32_16x16x32_bf16(ah1, Bh[1][1], z0, 0, 0, 0);
    z1 = __builtin_amdgcn_mfma_f32_16x16x32_bf16(ah3, Bh[1][3], z1, 0, 0, 0);
    n0 = __builtin_amdgcn_mfma_f32_16x16x32_bf16(ah1, Bh[2][1], n0, 0, 0, 0);
    n1 = __builtin_amdgcn_mfma_f32_16x16x32_bf16(ah3, Bh[2][3], n1, 0, 0, 0);

    float rr = frcp_(1.f + fexp2_(-(gxr + r0[0] + r1[0])));
    float zz = frcp_(1.f + fexp2_(-(gxz + z0[0] + z1[0])));
    float nn = 1.f - 2.f * frcp_(fexp2_(gxn + rr * (n0[0] + n1[0])) + 1.f);
    h = nn + zz * (h - nn);
    hsum += h;
    Abuf[p ^ 1][(q * 4) * AST + o] = f2b_trunc(h);
    asm volatile("s_waitcnt lgkmcnt(0)\n\ts_barrier" ::: "memory");
  }
  HS[((size_t)rec * BB + bg * 4 + q) * 128 + o] = hsum;
}

// ---------------------------------------------------------------------------
// Head: pooled -> Linear -> BN(eval) -> ReLU6 -> Linear.  grid=64, block=256.
// ---------------------------------------------------------------------------
__global__ __launch_bounds__(256) void head_kernel(
    const float* __restrict__ HS, const float* __restrict__ fW1,
    const float* __restrict__ fb1, const float* __restrict__ bng,
    const float* __restrict__ bnb, const float* __restrict__ fW2,
    const float* __restrict__ fb2, float* __restrict__ out) {
  __shared__ float pl[384];
  __shared__ float h1[256];
  int b = blockIdx.x, n = threadIdx.x;
  {
    int j = n;
    int seg = j >> 7, oo = j & 127;
    pl[j] = (HS[((size_t)seg * BB + b) * 128 + oo] +
             HS[((size_t)(seg + 3) * BB + b) * 128 + oo]) * (0.5f / 512.f);
  }
  if (n < 128) {
    int j = 256 + n;
    int seg = j >> 7, oo = j & 127;
    pl[j] = (HS[((size_t)seg * BB + b) * 128 + oo] +
             HS[((size_t)(seg + 3) * BB + b) * 128 + oo]) * (0.5f / 512.f);
  }
  __syncthreads();
  float acc = fb1[n];
  for (int k = 0; k < 384; ++k) acc += pl[k] * fW1[k * 256 + n];
  float hv = acc * rsqrtf(1.f + 1e-5f) * bng[n] + bnb[n];
  hv = fminf(fmaxf(hv, 0.f), 6.f);
  h1[n] = hv;
  __syncthreads();
  if (n < 8) {
    float a2 = fb2[n];
    for (int k = 0; k < 256; ++k) a2 += h1[k] * fW2[k * 8 + n];
    out[b * 8 + n] = a2;
  }
}

// ---------------------------------------------------------------------------
extern "C" void kernel_launch(void* const* d_in, const int* in_sizes, int n_in,
                              void* d_out, int out_size, void* d_ws,
                              size_t ws_size, hipStream_t stream) {
  (void)in_sizes; (void)n_in; (void)out_size; (void)ws_size;
  const float* text = (const float*)d_in[0];
  const float* vis  = (const float*)d_in[1];
  const float* aud  = (const float*)d_in[2];
  const float* fc1W = (const float*)d_in[3];
  const float* fc1b = (const float*)d_in[4];
  const float* fc2W = (const float*)d_in[5];
  const float* fc2b = (const float*)d_in[6];
  const float* fc3W = (const float*)d_in[7];
  const float* fc3b = (const float*)d_in[8];
  const float* Wq = (const float*)d_in[9];
  const float* bq = (const float*)d_in[10];
  const float* Wk = (const float*)d_in[11];
  const float* bk = (const float*)d_in[12];
  const float* Wv = (const float*)d_in[13];
  const float* bv = (const float*)d_in[14];
  const float* Wd = (const float*)d_in[15];
  const float* bd = (const float*)d_in[16];
  const float* lng = (const float*)d_in[17];
  const float* lnb = (const float*)d_in[18];
  const float* gWih = (const float*)d_in[19];
  const float* gWhh = (const float*)d_in[20];
  const float* gbih = (const float*)d_in[21];
  const float* gbhh = (const float*)d_in[22];
  const float* fW1 = (const float*)d_in[23];
  const float* fb1 = (const float*)d_in[24];
  const float* bng = (const float*)d_in[25];
  const float* bnb = (const float*)d_in[26];
  const float* fW2 = (const float*)d_in[27];
  const float* fb2 = (const float*)d_in[28];
  float* out = (float*)d_out;

  unsigned short* WSB = (unsigned short*)d_ws;
  unsigned short* T   = WSB;
  unsigned short* Vv  = WSB + SZ;
  unsigned short* Aa  = WSB + 2 * SZ;
  unsigned short* QKV = WSB + 3 * SZ;
  unsigned short* CTX = WSB + 12 * SZ;
  unsigned short* GXR = WSB;              // slices 0..17 ([6][32768][384])
  unsigned short* GRUIN = WSB + 18 * SZ;  // slices 18..20
  unsigned short* WB  = WSB + 21 * SZ;
  float* VS = (float*)(WSB + 21 * SZ + 1048576);
  float* HS = VS + 6 * 64 * 128;
  float* gbihs = HS + 6 * 64 * 128;       // 2304 floats
  float* bqs = gbihs + 6 * 384;           // 768 floats

  prep_kernel<<<dim3(1024), dim3(256), 0, stream>>>(
      fc1W, fc2W, fc3W, Wq, Wk, Wv, Wd, gWih, gWhh, gbih, gbhh, bq, WB,
      gbihs, bqs);
  hipMemsetAsync(VS, 0, 6 * 64 * 128 * sizeof(float), stream);

  {
    GArgs ga{};
    ga.gw = 1;
    ga.g[0] = {text, WB + WB_P1, fc1b, T, 300, 320, 1, 1, 128};  // abf=1: aligned
    ga.g[1] = {vis,  WB + WB_P2, fc2b, Vv, 35, 64, 0, 1, 128};
    ga.g[2] = {aud,  WB + WB_P3, fc3b, Aa, 74, 96, 0, 1, 128};
    gemm_proj<<<dim3(256, 1, 3), dim3(256), 0, stream>>>(ga);
  }

  const int qsel[6] = {0, 2, 0, 1, 1, 2};
  const int ksel[6] = {2, 0, 1, 0, 2, 1};
  unsigned short* proj[3] = {T, Vv, Aa};

  for (int phase = 0; phase < 2; ++phase) {
    // Grouped QKV: 3 A-groups (one per proj source), 2-4 W-tiles each.
    GArgs ga{};
    ga.gw = 4;
    int cnt[3] = {0, 0, 0};
    for (int ul = 0; ul < 3; ++ul) {
      int u = phase * 3 + ul;
      for (int op = 0; op < 3; ++op) {
        int a = (op == 0) ? qsel[u] : ksel[u];
        int z = ul * 3 + op;
        const float* bias = (op == 0) ? (bqs + u * 128)
                          : (op == 1) ? (bk + u * 128) : (bv + u * 128);
        float* vsum = (op == 2) ? (VS + (size_t)u * BB * DD) : nullptr;
        ga.g[a * 4 + cnt[a]] = {proj[a],
                                WB + WB_QKVD + op * 98304 + u * 16384, bias,
                                QKV + (size_t)z * SZ, 128, 128, 0, 1, 128,
                                vsum};
        cnt[a]++;
      }
    }
    for (int a = 0; a < 3; ++a) ga.g[a * 4].abf = cnt[a];
    gemm_k128g<<<dim3(256, 1, 3), dim3(256), 0, stream>>>(ga);
    attn2<<<dim3(2, 128, 3), dim3(256), 0, stream>>>(
        QKV, VS + phase * 3 * BB * DD, CTX + (size_t)phase * 3 * SZ);
  }

  // Fused dense+LN stage 1: GRUIN[g] = f2b(0.5 * LN(CTX_u @ Wd_u + bd_u)),
  // u = u1t[g]; stage 2 accumulates u2t[g].  Replaces DOUT + ln_pair.
  {
    const int u1t[3] = {1, 2, 0};
    GArgs ga{};
    ga.gw = 1;
    for (int g = 0; g < 3; ++g) {
      int u = u1t[g];
      ga.g[g] = {CTX + (size_t)u * SZ, WB + WB_QKVD + 3 * 98304 + u * 16384,
                 bd + u * 128, GRUIN + (size_t)g * SZ, 128, 128, 1, 0, 128,
                 nullptr, lng + u * 128, lnb + u * 128};
    }
    gemm_dln<<<dim3(256, 1, 3), dim3(256), 0, stream>>>(ga);
  }
  {
    const int u2t[3] = {3, 5, 4};
    GArgs ga{};
    ga.gw = 1;
    for (int g = 0; g < 3; ++g) {
      int u = u2t[g];
      ga.g[g] = {CTX + (size_t)u * SZ, WB + WB_QKVD + 3 * 98304 + u * 16384,
                 bd + u * 128, GRUIN + (size_t)g * SZ, 128, 128, 1, 1, 128,
                 nullptr, lng + u * 128, lnb + u * 128};
    }
    gemm_dln<<<dim3(256, 1, 3), dim3(256), 0, stream>>>(ga);
  }

  // gx = GRUIN[g] @ Wih[rec]^T + gbihs[rec] -> row-major GXR (coalesced).
  // Grouped: 3 A-groups (one per GRUIN slice) x 6 W-tiles (2 rec x 3 ny).
  {
    GArgs ga{};
    ga.gw = 6;
    for (int g = 0; g < 3; ++g) {
      for (int i = 0; i < 6; ++i) {
        int dr = i / 3, ny = i % 3, r6 = g * 2 + dr;
        ga.g[g * 6 + i] = {GRUIN + (size_t)g * SZ,
                           WB + WB_WIH + r6 * 49152 + ny * 16384,
                           gbihs + r6 * 384 + ny * 128,
                           GXR + (size_t)r6 * 12582912 + ny * 128,
                           128, 128, (i == 0) ? 6 : 0, 1, 384, nullptr};
      }
    }
    gemm_k128g<<<dim3(256, 1, 3), dim3(256), 0, stream>>>(ga);
  }

  gru8<<<dim3(16, 6), dim3(512), 0, stream>>>(GXR, WB, gbhh, HS);
  head_kernel<<<dim3(BB), dim3(256), 0, stream>>>(HS, fW1, fb1, bng, bnb, fW2, fb2, out);
}

// Round 11
// 674.712 us; speedup vs baseline: 1.0318x; 1.0318x over previous
//
#include <hip/hip_runtime.h>
#include <hip/hip_bf16.h>

// Problem constants
#define BB 64
#define SS 512
#define DD 128
#define NROW (BB * SS)          // 32768
#define SZ ((size_t)NROW * DD)  // 4,194,304 elems per [B,S,128] slice

#define LOG2E 1.4426950408889634f
#define QSCALE (0.125f * LOG2E)

typedef __attribute__((ext_vector_type(8))) short short8;
typedef __attribute__((ext_vector_type(4))) float f32x4;

// WB (converted-weight buffer) element offsets, all bf16:
#define WB_P1 0          // fc1W^T [128][320] (K=300 pad 320)
#define WB_P2 40960      // fc2W^T [128][64]  (K=35 pad 64)
#define WB_P3 49152      // fc3W^T [128][96]  (K=74 pad 96)
#define WB_QKVD 61440    // [4 op][6 u][128 n][128 k]  (op0=Wq prescaled by QSCALE)
#define WB_WIH 454656    // [6 rec][384 n][128 k]  (prescaled by log2e/2log2e)
#define WB_WHH 749568    // [6 rec][384 n][128 k]  (prescaled by log2e/2log2e)
#define WB_TOTAL 1044480

__device__ __forceinline__ float frcp_(float x) { return __builtin_amdgcn_rcpf(x); }
__device__ __forceinline__ float fexp2_(float x) { return __builtin_amdgcn_exp2f(x); }
__device__ __forceinline__ float b2f(unsigned short u) {
  union { unsigned int i; float f; } x; x.i = ((unsigned int)u) << 16; return x.f;
}
__device__ __forceinline__ unsigned short f2b(float f) {
  __hip_bfloat16 b = __float2bfloat16(f);
  return *reinterpret_cast<unsigned short*>(&b);
}
__device__ __forceinline__ unsigned short f2b_trunc(float f) {
  union { float f; unsigned int i; } x; x.f = f; return (unsigned short)(x.i >> 16);
}

// ---------------------------------------------------------------------------
// Weight prep.  Wq prescaled by QSCALE; GRU weights prescaled by log2e (r,z)
// / 2log2e (n).  gbihs = scale*(gbih + gbhh) for r,z gates; for n gate
// gbihs = scale*gbih only (bhh_n carried by gru kernel's cbhn accumulator).
// ---------------------------------------------------------------------------
__global__ __launch_bounds__(256) void prep_kernel(
    const float* __restrict__ fc1W, const float* __restrict__ fc2W,
    const float* __restrict__ fc3W, const float* __restrict__ Wq,
    const float* __restrict__ Wk, const float* __restrict__ Wv,
    const float* __restrict__ Wd, const float* __restrict__ gWih,
    const float* __restrict__ gWhh, const float* __restrict__ gbih,
    const float* __restrict__ gbhh, const float* __restrict__ bq,
    unsigned short* __restrict__ WB, float* __restrict__ gbihs,
    float* __restrict__ bqs) {
  for (int idx = blockIdx.x * 256 + threadIdx.x; idx < WB_TOTAL;
       idx += gridDim.x * 256) {
    float v;
    if (idx < WB_P2) {
      int n = idx / 320, k = idx % 320;
      v = (k < 300) ? fc1W[k * 128 + n] : 0.f;
    } else if (idx < WB_P3) {
      int r = idx - WB_P2; int n = r >> 6, k = r & 63;
      v = (k < 35) ? fc2W[k * 128 + n] : 0.f;
    } else if (idx < WB_QKVD) {
      int r = idx - WB_P3; int n = r / 96, k = r % 96;
      v = (k < 74) ? fc3W[k * 128 + n] : 0.f;
    } else if (idx < WB_WIH) {
      int r = idx - WB_QKVD;
      int op = r / 98304; int r2 = r % 98304;
      int u = r2 >> 14; int r3 = r2 & 16383;
      int n = r3 >> 7, k = r3 & 127;
      const float* src = (op == 0) ? Wq : (op == 1) ? Wk : (op == 2) ? Wv : Wd;
      v = src[u * 16384 + k * 128 + n];
      if (op == 0) v *= QSCALE;
    } else if (idx < WB_WHH) {
      int r = idx - WB_WIH;
      int r3 = r % 49152;  // within rec: [384 n][128 k]
      int gate = (r3 >> 7) >> 7;
      v = gWih[r] * (gate < 2 ? LOG2E : 2.f * LOG2E);
    } else {
      int r = idx - WB_WHH;
      int r3 = r % 49152;
      int gate = (r3 >> 7) >> 7;
      v = gWhh[r] * (gate < 2 ? LOG2E : 2.f * LOG2E);
    }
    WB[idx] = f2b(v);
  }
  for (int idx = blockIdx.x * 256 + threadIdx.x; idx < 6 * 384;
       idx += gridDim.x * 256) {
    int gate = (idx % 384) >> 7;
    float v = gbih[idx] + (gate < 2 ? gbhh[idx] : 0.f);
    gbihs[idx] = v * (gate < 2 ? LOG2E : 2.f * LOG2E);
  }
  for (int idx = blockIdx.x * 256 + threadIdx.x; idx < 6 * 128;
       idx += gridDim.x * 256) {
    bqs[idx] = bq[idx] * QSCALE;
  }
}

// ---------------------------------------------------------------------------
// GArg: shared by all gemm kernels.  For gemm_k128g, entries are grouped in
// blocks of `gw` sharing one A tile; abf of a group's FIRST entry = number of
// live entries (nw).  For gemm_proj, abf=1 marks 16B-aligned f32 A rows.
// For gemm_dln2: entries come in pairs (gw=2) -- one per unit of the group;
// g2/b2 = LN gamma/beta (pre-offset); C of the FIRST entry = output.
// ---------------------------------------------------------------------------
struct GArg {
  const void* A; const unsigned short* W; const float* bias; void* C;
  int Ka, Kp, abf, cbf, cs; float* vsum;
  const float* g2; const float* b2;
};
struct GArgs { GArg g[18]; int gw; int pad_; };

#define CST 5120  // chunk stride in shorts (128 rows * 40)

// ---------------------------------------------------------------------------
// gemm_proj: staged whole-tile path for the f32-input projections.
// Stages of up to 96 k-cols (3 chunks, 60KB LDS): {stage A(f32->bf16,
// float4-vectorized when abf) + W -> barrier -> nc x 16 MFMA -> barrier}.
// (R8: -14us vs per-32 loop.)
// ---------------------------------------------------------------------------
__global__ __launch_bounds__(256) void gemm_proj(GArgs args) {
  const GArg ga = args.g[blockIdx.z];
  __shared__ unsigned short As[3 * CST];
  __shared__ unsigned short Ws[3 * CST];
  const int t = threadIdx.x;
  const int lane = t & 63, q = lane >> 4, lm = lane & 15;
  const int w = t >> 6, wm = w >> 1, wn = w & 1;
  const int m0 = blockIdx.x * 128;
  const int row = t >> 1, half = t & 1;

  f32x4 acc[4][4];
#pragma unroll
  for (int i = 0; i < 4; ++i)
#pragma unroll
    for (int j = 0; j < 4; ++j) acc[i][j] = (f32x4){0.f, 0.f, 0.f, 0.f};

  const float* Ab = (const float*)ga.A + (size_t)(m0 + row) * ga.Ka;
  const unsigned short* Wb = ga.W + (size_t)row * ga.Kp;

  for (int k0 = 0; k0 < ga.Kp; k0 += 96) {
    const int SW = (ga.Kp - k0 < 96) ? (ga.Kp - k0) : 96;  // 96/64/32, mult 32
    const int hw = SW >> 1;                                // 48/32/16 cols/thread
    const int cbase = half * hw;
    if (k0) __syncthreads();  // prior stage fully consumed

    if (ga.abf) {
      // 16B-aligned rows, Ka%4==0: whole-granule masking, float4 loads.
#pragma unroll 4
      for (int j = 0; j < hw; j += 4) {
        const int cg = k0 + cbase + j;
        float4 v = {0.f, 0.f, 0.f, 0.f};
        if (cg + 4 <= ga.Ka) v = *reinterpret_cast<const float4*>(Ab + cg);
        const int cc = cbase + j, lc = cc >> 5, co = cc & 31;
        unsigned short tp[4] = {f2b(v.x), f2b(v.y), f2b(v.z), f2b(v.w)};
        *reinterpret_cast<unsigned long long*>(&As[lc * CST + row * 40 + co]) =
            *reinterpret_cast<unsigned long long*>(tp);
      }
    } else {
      // misaligned rows (vis/aud): scalar masked loads (single-stage slices).
#pragma unroll 4
      for (int j = 0; j < hw; j += 4) {
        const int cg = k0 + cbase + j;
        unsigned short tp[4];
#pragma unroll
        for (int e = 0; e < 4; ++e)
          tp[e] = (cg + e < ga.Ka) ? f2b(Ab[cg + e]) : (unsigned short)0;
        const int cc = cbase + j, lc = cc >> 5, co = cc & 31;
        *reinterpret_cast<unsigned long long*>(&As[lc * CST + row * 40 + co]) =
            *reinterpret_cast<unsigned long long*>(tp);
      }
    }
    // W stage: bf16, rows are 16B-multiples (Kp mult of 32).
#pragma unroll 2
    for (int j = 0; j < hw; j += 8) {
      const int cg = k0 + cbase + j;
      short8 v = *reinterpret_cast<const short8*>(Wb + cg);
      const int cc = cbase + j, lc = cc >> 5, co = cc & 31;
      *reinterpret_cast<short8*>(&Ws[lc * CST + row * 40 + co]) = v;
    }
    __syncthreads();

    const int nc = SW >> 5;
    for (int c = 0; c < nc; ++c) {
      short8 af[4], bfv[4];
#pragma unroll
      for (int mi = 0; mi < 4; ++mi)
        af[mi] = *reinterpret_cast<const short8*>(
            &As[c * CST + (wm * 64 + mi * 16 + lm) * 40 + q * 8]);
#pragma unroll
      for (int ni = 0; ni < 4; ++ni)
        bfv[ni] = *reinterpret_cast<const short8*>(
            &Ws[c * CST + (wn * 64 + ni * 16 + lm) * 40 + q * 8]);
#pragma unroll
      for (int mi = 0; mi < 4; ++mi)
#pragma unroll
        for (int ni = 0; ni < 4; ++ni)
          acc[mi][ni] = __builtin_amdgcn_mfma_f32_16x16x32_bf16(
              af[mi], bfv[ni], acc[mi][ni], 0, 0, 0);
    }
  }

#pragma unroll
  for (int ni = 0; ni < 4; ++ni) {
    const int colg = wn * 64 + ni * 16 + lm;
    const float bv = ga.bias[colg];
#pragma unroll
    for (int mi = 0; mi < 4; ++mi) {
      const int rg = m0 + wm * 64 + mi * 16 + q * 4;
#pragma unroll
      for (int r = 0; r < 4; ++r) {
        float v = acc[mi][ni][r] + bv;
        ((unsigned short*)ga.C)[(size_t)(rg + r) * ga.cs + colg] = f2b(v);
      }
    }
  }
}

// ---------------------------------------------------------------------------
// gemm_k128g: grouped whole-tile path for bf16 A, K==128 slices.
// grid z = A-group.  Stage the group's shared 128x128 A tile ONCE, then loop
// over its nw W-tiles: {stage W -> barrier -> 64 MFMA -> epilogue -> barrier}.
// (R7: -23us vs per-z launches.)
// ---------------------------------------------------------------------------
__global__ __launch_bounds__(256) void gemm_k128g(GArgs args) {
  const int base = blockIdx.z * args.gw;
  const int nw = args.g[base].abf;
  __shared__ unsigned short As4[4 * CST];
  __shared__ unsigned short Ws4[4 * CST];
  const int t = threadIdx.x;
  const int lane = t & 63, q = lane >> 4, lm = lane & 15;
  const int w = t >> 6, wm = w >> 1, wn = w & 1;
  const int m0 = blockIdx.x * 128;

  // staging geometry: thread covers rows (t>>4)+16p, col octet (t&15)*8
  const int srow = t >> 4, scol = (t & 15) * 8;
  const int sc = scol >> 5, soff = scol & 31;

  {  // stage shared A tile once
    const unsigned short* Ab =
        (const unsigned short*)args.g[base].A + (size_t)(m0 + srow) * 128 + scol;
#pragma unroll
    for (int p = 0; p < 8; ++p) {
      short8 av = *reinterpret_cast<const short8*>(Ab + (size_t)p * 16 * 128);
      *reinterpret_cast<short8*>(&As4[sc * CST + (srow + p * 16) * 40 + soff]) = av;
    }
  }

  for (int i = 0; i < nw; ++i) {
    const GArg ge = args.g[base + i];
    if (i) __syncthreads();  // all waves done reading Ws4 of entry i-1
    {
      const unsigned short* Wg = ge.W + (size_t)srow * 128 + scol;
#pragma unroll
      for (int p = 0; p < 8; ++p) {
        short8 wv = *reinterpret_cast<const short8*>(Wg + (size_t)p * 16 * 128);
        *reinterpret_cast<short8*>(&Ws4[sc * CST + (srow + p * 16) * 40 + soff]) = wv;
      }
    }
    __syncthreads();

    f32x4 acc[4][4];
#pragma unroll
    for (int ii = 0; ii < 4; ++ii)
#pragma unroll
      for (int jj = 0; jj < 4; ++jj) acc[ii][jj] = (f32x4){0.f, 0.f, 0.f, 0.f};

#pragma unroll
    for (int c = 0; c < 4; ++c) {
      short8 af[4], bfv[4];
#pragma unroll
      for (int mi = 0; mi < 4; ++mi)
        af[mi] = *reinterpret_cast<const short8*>(
            &As4[c * CST + (wm * 64 + mi * 16 + lm) * 40 + q * 8]);
#pragma unroll
      for (int ni = 0; ni < 4; ++ni)
        bfv[ni] = *reinterpret_cast<const short8*>(
            &Ws4[c * CST + (wn * 64 + ni * 16 + lm) * 40 + q * 8]);
#pragma unroll
      for (int mi = 0; mi < 4; ++mi)
#pragma unroll
        for (int ni = 0; ni < 4; ++ni)
          acc[mi][ni] = __builtin_amdgcn_mfma_f32_16x16x32_bf16(
              af[mi], bfv[ni], acc[mi][ni], 0, 0, 0);
    }

#pragma unroll
    for (int ni = 0; ni < 4; ++ni) {
      const int colg = wn * 64 + ni * 16 + lm;
      const float bv = ge.bias[colg];
#pragma unroll
      for (int mi = 0; mi < 4; ++mi) {
        const int rg = m0 + wm * 64 + mi * 16 + q * 4;
#pragma unroll
        for (int r = 0; r < 4; ++r) {
          float v = acc[mi][ni][r] + bv;
          ((unsigned short*)ge.C)[(size_t)(rg + r) * ge.cs + colg] = f2b(v);
        }
      }
    }
    if (ge.vsum) {
      float* vp = ge.vsum + (size_t)(m0 >> 9) * 128;
#pragma unroll
      for (int ni = 0; ni < 4; ++ni) {
        const int colg = wn * 64 + ni * 16 + lm;
        float s = 16.f * ge.bias[colg];
#pragma unroll
        for (int mi = 0; mi < 4; ++mi)
#pragma unroll
          for (int r = 0; r < 4; ++r) s += acc[mi][ni][r];
        atomicAdd(&vp[colg], s);
      }
    }
  }
}

// ---------------------------------------------------------------------------
// gemm_dln2: DUAL-unit dense Wd GEMM with fused LayerNorm epilogue.
// R10's two-stage dln was NEUTRAL (two sequential half-GPU launches + GRUIN
// read-modify-write offset the traffic win).  v2: ONE launch (grid 256x3);
// each block computes BOTH units of its group back-to-back (LDS reused),
// LNs both accumulator sets, and writes GRUIN = 0.5*LN1 + 0.5*LN2 once.
// Removes: 1 launch, 1 dispatch tail, stage1<->stage2 dependency, 48MB
// GRUIN round trip.  Pair-sum in f32 before one rounding (reference-closer).
// LB stats: float4 (s1,sq1,s2,sq2) per (row,wn) in dead As4 LDS.
// ---------------------------------------------------------------------------
__global__ __launch_bounds__(256) void gemm_dln2(GArgs args) {
  const GArg g1 = args.g[blockIdx.z * 2];
  const GArg g2e = args.g[blockIdx.z * 2 + 1];
  __shared__ unsigned short As4[4 * CST];
  __shared__ unsigned short Ws4[4 * CST];
  const int t = threadIdx.x;
  const int lane = t & 63, q = lane >> 4, lm = lane & 15;
  const int w = t >> 6, wm = w >> 1, wn = w & 1;
  const int m0 = blockIdx.x * 128;

  const int srow = t >> 4, scol = (t & 15) * 8;
  const int sc = scol >> 5, soff = scol & 31;

  f32x4 acc1[4][4], acc2[4][4];
#pragma unroll
  for (int i = 0; i < 4; ++i)
#pragma unroll
    for (int j = 0; j < 4; ++j) {
      acc1[i][j] = (f32x4){0.f, 0.f, 0.f, 0.f};
      acc2[i][j] = (f32x4){0.f, 0.f, 0.f, 0.f};
    }

#pragma unroll
  for (int pass = 0; pass < 2; ++pass) {
    const GArg& ge = pass ? g2e : g1;
    if (pass) __syncthreads();  // prior pass's LDS fully consumed
    {
      const unsigned short* Ab =
          (const unsigned short*)ge.A + (size_t)(m0 + srow) * 128 + scol;
      const unsigned short* Wg = ge.W + (size_t)srow * 128 + scol;
#pragma unroll
      for (int p = 0; p < 8; ++p) {
        short8 av = *reinterpret_cast<const short8*>(Ab + (size_t)p * 16 * 128);
        short8 wv = *reinterpret_cast<const short8*>(Wg + (size_t)p * 16 * 128);
        *reinterpret_cast<short8*>(&As4[sc * CST + (srow + p * 16) * 40 + soff]) = av;
        *reinterpret_cast<short8*>(&Ws4[sc * CST + (srow + p * 16) * 40 + soff]) = wv;
      }
    }
    __syncthreads();

#pragma unroll
    for (int c = 0; c < 4; ++c) {
      short8 af[4], bfv[4];
#pragma unroll
      for (int mi = 0; mi < 4; ++mi)
        af[mi] = *reinterpret_cast<const short8*>(
            &As4[c * CST + (wm * 64 + mi * 16 + lm) * 40 + q * 8]);
#pragma unroll
      for (int ni = 0; ni < 4; ++ni)
        bfv[ni] = *reinterpret_cast<const short8*>(
            &Ws4[c * CST + (wn * 64 + ni * 16 + lm) * 40 + q * 8]);
#pragma unroll
      for (int mi = 0; mi < 4; ++mi)
#pragma unroll
        for (int ni = 0; ni < 4; ++ni) {
          if (pass == 0)
            acc1[mi][ni] = __builtin_amdgcn_mfma_f32_16x16x32_bf16(
                af[mi], bfv[ni], acc1[mi][ni], 0, 0, 0);
          else
            acc2[mi][ni] = __builtin_amdgcn_mfma_f32_16x16x32_bf16(
                af[mi], bfv[ni], acc2[mi][ni], 0, 0, 0);
        }
    }
  }

  // ---- fused dual LN epilogue ----
  float bv1[4], gg1[4], bb1[4], bv2[4], gg2[4], bb2[4];
#pragma unroll
  for (int ni = 0; ni < 4; ++ni) {
    const int colg = wn * 64 + ni * 16 + lm;
    bv1[ni] = g1.bias[colg]; gg1[ni] = g1.g2[colg]; bb1[ni] = g1.b2[colg];
    bv2[ni] = g2e.bias[colg]; gg2[ni] = g2e.g2[colg]; bb2[ni] = g2e.b2[colg];
  }
  float s1[4][4], q1[4][4], s2[4][4], q2[4][4];  // [mi][r]
#pragma unroll
  for (int mi = 0; mi < 4; ++mi)
#pragma unroll
    for (int r = 0; r < 4; ++r) {
      float a1 = 0.f, c1 = 0.f, a2 = 0.f, c2 = 0.f;
#pragma unroll
      for (int ni = 0; ni < 4; ++ni) {
        float v1 = acc1[mi][ni][r] + bv1[ni];
        float v2 = acc2[mi][ni][r] + bv2[ni];
        a1 += v1; c1 += v1 * v1;
        a2 += v2; c2 += v2 * v2;
      }
      s1[mi][r] = a1; q1[mi][r] = c1; s2[mi][r] = a2; q2[mi][r] = c2;
    }
#pragma unroll
  for (int m = 1; m < 16; m <<= 1)
#pragma unroll
    for (int mi = 0; mi < 4; ++mi)
#pragma unroll
      for (int r = 0; r < 4; ++r) {
        s1[mi][r] += __shfl_xor(s1[mi][r], m);
        q1[mi][r] += __shfl_xor(q1[mi][r], m);
        s2[mi][r] += __shfl_xor(s2[mi][r], m);
        q2[mi][r] += __shfl_xor(q2[mi][r], m);
      }
  // cross-wave (wn) combine through LB aliased into As4 (dead after MFMA).
  float4* LB = reinterpret_cast<float4*>(As4);  // [row][wn] -> (s1,q1,s2,q2)
  __syncthreads();  // all MFMA LDS reads done before overwriting As4
  if (lm == 0) {
#pragma unroll
    for (int mi = 0; mi < 4; ++mi)
#pragma unroll
      for (int r = 0; r < 4; ++r) {
        float4 p;
        p.x = s1[mi][r]; p.y = q1[mi][r]; p.z = s2[mi][r]; p.w = q2[mi][r];
        LB[(wm * 64 + mi * 16 + q * 4 + r) * 2 + wn] = p;
      }
  }
  __syncthreads();

#pragma unroll
  for (int mi = 0; mi < 4; ++mi)
#pragma unroll
    for (int r = 0; r < 4; ++r) {
      float4 oth = LB[(wm * 64 + mi * 16 + q * 4 + r) * 2 + (wn ^ 1)];
      const float m1 = (s1[mi][r] + oth.x) * (1.f / 128.f);
      const float va1 = (q1[mi][r] + oth.y) * (1.f / 128.f) - m1 * m1;
      const float rs1 = rsqrtf(va1 + 1e-5f);
      const float m2 = (s2[mi][r] + oth.z) * (1.f / 128.f);
      const float va2 = (q2[mi][r] + oth.w) * (1.f / 128.f) - m2 * m2;
      const float rs2 = rsqrtf(va2 + 1e-5f);
      const int rg = m0 + wm * 64 + mi * 16 + q * 4 + r;
      unsigned short* cp = (unsigned short*)g1.C + (size_t)rg * 128;
#pragma unroll
      for (int ni = 0; ni < 4; ++ni) {
        const int colg = wn * 64 + ni * 16 + lm;
        float v1 = acc1[mi][ni][r] + bv1[ni];
        float v2 = acc2[mi][ni][r] + bv2[ni];
        float o = 0.5f * ((v1 - m1) * rs1 * gg1[ni] + bb1[ni]) +
                  0.5f * ((v2 - m2) * rs2 * gg2[ni] + bb2[ni]);
        cp[colg] = f2b(o);
      }
    }
}

// ---------------------------------------------------------------------------
// MFMA attention v2 (probs = 1 - softmax): ctx = Vsum - softmax(QK^T/8) @ V.
// grid = (2 q-halves, 128 = b*2+h, 3 units), block = 256 (4 waves).
// (round-4 version verbatim; round-5's swapped-PV/SB variant regressed.)
// ---------------------------------------------------------------------------
__global__ __launch_bounds__(256) void attn2(
    const unsigned short* __restrict__ QKV, const float* __restrict__ VS,
    unsigned short* __restrict__ CTX) {
  __shared__ unsigned short Vt[64 * 72];       // [d][k ^ (d&56)]
  __shared__ unsigned short Pt[4][16 * 72];    // per-wave [q][k]
  const int t = threadIdx.x;
  const int w = t >> 6, lane = t & 63, quad = lane >> 4, lm = lane & 15;
  const int z = blockIdx.z;
  const int bh = blockIdx.y, b = bh >> 1, h = bh & 1;
  const int qbase = blockIdx.x * 256;

  const unsigned short* Qg = QKV + (size_t)(z * 3 + 0) * SZ;
  const unsigned short* Kg = QKV + (size_t)(z * 3 + 1) * SZ;
  const unsigned short* Vg = QKV + (size_t)(z * 3 + 2) * SZ;

  short8 aq[4][2];
#pragma unroll
  for (int qt = 0; qt < 4; ++qt)
#pragma unroll
    for (int c = 0; c < 2; ++c)
      aq[qt][c] = *reinterpret_cast<const short8*>(
          Qg + ((size_t)(b * SS + qbase + qt * 64 + w * 16 + lm)) * DD +
          h * 64 + c * 32 + quad * 8);

  const f32x4 czero = {0.f, 0.f, 0.f, 0.f};
  f32x4 o[4][4];  // [qt][dt]
#pragma unroll
  for (int i = 0; i < 4; ++i)
#pragma unroll
    for (int j = 0; j < 4; ++j) o[i][j] = czero;
  float suml[4][4];  // [qt][r]
#pragma unroll
  for (int i = 0; i < 4; ++i)
#pragma unroll
    for (int j = 0; j < 4; ++j) suml[i][j] = 0.f;

  const int vk = t >> 3, vd0 = (t & 7) * 8;

  for (int kt = 0; kt < 8; ++kt) {
    const int k0 = kt * 64;
    __syncthreads();  // prior Vt fully consumed (bv regs read)
#pragma unroll
    for (int i = 0; i < 2; ++i) {
      const int k = vk + i * 32;
      short8 vv = *reinterpret_cast<const short8*>(
          Vg + ((size_t)(b * SS + k0 + k)) * DD + h * 64 + vd0);
#pragma unroll
      for (int j = 0; j < 8; ++j) {
        const int d = vd0 + j;
        Vt[d * 72 + (k ^ (d & 56))] = (unsigned short)vv[j];
      }
    }
    __syncthreads();

    short8 bk[4][2];
#pragma unroll
    for (int nt = 0; nt < 4; ++nt)
#pragma unroll
      for (int c = 0; c < 2; ++c)
        bk[nt][c] = *reinterpret_cast<const short8*>(
            Kg + ((size_t)(b * SS + k0 + nt * 16 + lm)) * DD + h * 64 +
            c * 32 + quad * 8);
    short8 bvv[4][2];
#pragma unroll
    for (int dt = 0; dt < 4; ++dt) {
      const int d = dt * 16 + lm;
#pragma unroll
      for (int c = 0; c < 2; ++c)
        bvv[dt][c] = *reinterpret_cast<const short8*>(
            &Vt[d * 72 + ((c * 32 + quad * 8) ^ (d & 56))]);
    }

#pragma unroll
    for (int qt = 0; qt < 4; ++qt) {
      f32x4 sacc[4];
#pragma unroll
      for (int nt = 0; nt < 4; ++nt)
        sacc[nt] = __builtin_amdgcn_mfma_f32_16x16x32_bf16(
            aq[qt][0], bk[nt][0], czero, 0, 0, 0);
#pragma unroll
      for (int nt = 0; nt < 4; ++nt)
        sacc[nt] = __builtin_amdgcn_mfma_f32_16x16x32_bf16(
            aq[qt][1], bk[nt][1], sacc[nt], 0, 0, 0);
#pragma unroll
      for (int nt = 0; nt < 4; ++nt) {
#pragma unroll
        for (int r = 0; r < 4; ++r) {
          float p = fexp2_(sacc[nt][r]);
          suml[qt][r] += p;
          Pt[w][(quad * 4 + r) * 72 + nt * 16 + lm] = f2b_trunc(p);
        }
      }
#pragma unroll
      for (int c = 0; c < 2; ++c) {
        short8 ap = *reinterpret_cast<const short8*>(
            &Pt[w][lm * 72 + c * 32 + quad * 8]);
#pragma unroll
        for (int dt = 0; dt < 4; ++dt)
          o[qt][dt] = __builtin_amdgcn_mfma_f32_16x16x32_bf16(
              ap, bvv[dt][c], o[qt][dt], 0, 0, 0);
      }
    }
  }
#pragma unroll
  for (int qt = 0; qt < 4; ++qt)
#pragma unroll
    for (int r = 0; r < 4; ++r) {
#pragma unroll
      for (int m = 1; m < 16; m <<= 1)
        suml[qt][r] += __shfl_xor(suml[qt][r], m);
    }
  const float* vsp = VS + (size_t)(z * BB + b) * DD + h * 64;
#pragma unroll
  for (int qt = 0; qt < 4; ++qt)
#pragma unroll
    for (int dt = 0; dt < 4; ++dt) {
      const int col = dt * 16 + lm;
      const float vs = vsp[col];
#pragma unroll
      for (int r = 0; r < 4; ++r) {
        const int row = qbase + qt * 64 + w * 16 + quad * 4 + r;
        CTX[(size_t)z * SZ + ((size_t)(b * SS + row)) * DD + h * 64 + col] =
            f2b(vs - o[qt][dt][r] * frcp_(suml[qt][r]));
      }
    }
}

// ---------------------------------------------------------------------------
// GRU v10 (confirmed best: 173-175us, stable across rounds).  Do not
// restructure (v11 regressed).  grid = (16 bg, 6 rec), block = 512 (8 waves).
// ---------------------------------------------------------------------------
#define AST 136

__global__ __launch_bounds__(512, 1) void gru8(
    const unsigned short* __restrict__ GXR, const unsigned short* __restrict__ WB,
    const float* __restrict__ gbhh, float* __restrict__ HS) {
  __shared__ unsigned short Abuf[2][16 * AST];
  const int rec = blockIdx.y, bg = blockIdx.x;
  const int dir = rec & 1;
  const int t = threadIdx.x;
  const int w = t >> 6, lane = t & 63, q = lane >> 4, lm = lane & 15;
  const int o = w * 16 + lm;
  const int b = bg * 4 + q;

  short8 Bh[3][4];
  const unsigned short* whh = WB + WB_WHH + (size_t)rec * 49152;
#pragma unroll
  for (int gate = 0; gate < 3; ++gate)
#pragma unroll
    for (int c = 0; c < 4; ++c)
      Bh[gate][c] = *reinterpret_cast<const short8*>(
          whh + (size_t)(gate * 128 + o) * 128 + c * 32 + q * 8);
  const float bhn = gbhh[rec * 384 + 256 + o] * (2.f * LOG2E);
  const f32x4 czero = {0.f, 0.f, 0.f, 0.f};
  const f32x4 cbhn = {bhn, 0.f, 0.f, 0.f};

  float h = 0.f, hsum = 0.f;
  for (int i = t; i < 2 * 16 * AST; i += 512)
    (&Abuf[0][0])[i] = 0;

  // gx: 3 ushort loads/step from GXR[rec][b*512 + tt][384] at cols g*128+o.
  const unsigned short* gx0 = GXR + (size_t)rec * 12582912 +
      ((size_t)b * 512 + (dir ? 511 : 0)) * 384 + o;
  const ptrdiff_t st = dir ? -384 : 384;

  unsigned short ring[4][3];
#pragma unroll
  for (int pp = 0; pp < 4; ++pp) {
    const unsigned short* gp = gx0 + (ptrdiff_t)pp * st;
#pragma unroll
    for (int j = 0; j < 3; ++j) ring[pp][j] = gp[j * 128];
  }
  const unsigned short* pf = gx0 + (ptrdiff_t)4 * st;  // prefetch ptr (s+4)
  __syncthreads();

#pragma unroll 4
  for (int s = 0; s < SS; ++s) {
    const int p = s & 1, slot = s & 3;
    const float gxr = b2f(ring[slot][0]);
    const float gxz = b2f(ring[slot][1]);
    const float gxn = b2f(ring[slot][2]);
#pragma unroll
    for (int j = 0; j < 3; ++j) ring[slot][j] = pf[j * 128];
    pf += (s < SS - 5) ? st : 0;  // uniform-cond pointer bump, stays in-bounds

    short8 ah0 = *reinterpret_cast<const short8*>(&Abuf[p][lm * AST + 0 + q * 8]);
    short8 ah1 = *reinterpret_cast<const short8*>(&Abuf[p][lm * AST + 32 + q * 8]);
    short8 ah2 = *reinterpret_cast<const short8*>(&Abuf[p][lm * AST + 64 + q * 8]);
    short8 ah3 = *reinterpret_cast<const short8*>(&Abuf[p][lm * AST + 96 + q * 8]);
    f32x4 r0 = __builtin_amdgcn_mfma_f32_16x16x32_bf16(ah0, Bh[0][0], czero, 0, 0, 0);
    f32x4 r1 = __builtin_amdgcn_mfma_f32_16x16x32_bf16(ah2, Bh[0][2], czero, 0, 0, 0);
    f32x4 z0 = __builtin_amdgcn_mfma_f32_16x16x32_bf16(ah0, Bh[1][0], czero, 0, 0, 0);
    f32x4 z1 = __builtin_amdgcn_mfma_f32_16x16x32_bf16(ah2, Bh[1][2], czero, 0, 0, 0);
    f32x4 n0 = __builtin_amdgcn_mfma_f32_16x16x32_bf16(ah0, Bh[2][0], cbhn, 0, 0, 0);
    f32x4 n1 = __builtin_amdgcn_mfma_f32_16x16x32_bf16(ah2, Bh[2][2], czero, 0, 0, 0);
    r0 = __builtin_amdgcn_mfma_f32_16x16x32_bf16(ah1, Bh[0][1], r0, 0, 0, 0);
    r1 = __builtin_amdgcn_mfma_f32_16x16x32_bf16(ah3, Bh[0][3], r1, 0, 0, 0);
    z0 = __builtin_amdgcn_mfma_f32_16x16x32_bf16(ah1, Bh[1][1], z0, 0, 0, 0);
    z1 = __builtin_amdgcn_mfma_f32_16x16x32_bf16(ah3, Bh[1][3], z1, 0, 0, 0);
    n0 = __builtin_amdgcn_mfma_f32_16x16x32_bf16(ah1, Bh[2][1], n0, 0, 0, 0);
    n1 = __builtin_amdgcn_mfma_f32_16x16x32_bf16(ah3, Bh[2][3], n1, 0, 0, 0);

    float rr = frcp_(1.f + fexp2_(-(gxr + r0[0] + r1[0])));
    float zz = frcp_(1.f + fexp2_(-(gxz + z0[0] + z1[0])));
    float nn = 1.f - 2.f * frcp_(fexp2_(gxn + rr * (n0[0] + n1[0])) + 1.f);
    h = nn + zz * (h - nn);
    hsum += h;
    Abuf[p ^ 1][(q * 4) * AST + o] = f2b_trunc(h);
    asm volatile("s_waitcnt lgkmcnt(0)\n\ts_barrier" ::: "memory");
  }
  HS[((size_t)rec * BB + bg * 4 + q) * 128 + o] = hsum;
}

// ---------------------------------------------------------------------------
// Head: pooled -> Linear -> BN(eval) -> ReLU6 -> Linear.  grid=64, block=256.
// ---------------------------------------------------------------------------
__global__ __launch_bounds__(256) void head_kernel(
    const float* __restrict__ HS, const float* __restrict__ fW1,
    const float* __restrict__ fb1, const float* __restrict__ bng,
    const float* __restrict__ bnb, const float* __restrict__ fW2,
    const float* __restrict__ fb2, float* __restrict__ out) {
  __shared__ float pl[384];
  __shared__ float h1[256];
  int b = blockIdx.x, n = threadIdx.x;
  {
    int j = n;
    int seg = j >> 7, oo = j & 127;
    pl[j] = (HS[((size_t)seg * BB + b) * 128 + oo] +
             HS[((size_t)(seg + 3) * BB + b) * 128 + oo]) * (0.5f / 512.f);
  }
  if (n < 128) {
    int j = 256 + n;
    int seg = j >> 7, oo = j & 127;
    pl[j] = (HS[((size_t)seg * BB + b) * 128 + oo] +
             HS[((size_t)(seg + 3) * BB + b) * 128 + oo]) * (0.5f / 512.f);
  }
  __syncthreads();
  float acc = fb1[n];
  for (int k = 0; k < 384; ++k) acc += pl[k] * fW1[k * 256 + n];
  float hv = acc * rsqrtf(1.f + 1e-5f) * bng[n] + bnb[n];
  hv = fminf(fmaxf(hv, 0.f), 6.f);
  h1[n] = hv;
  __syncthreads();
  if (n < 8) {
    float a2 = fb2[n];
    for (int k = 0; k < 256; ++k) a2 += h1[k] * fW2[k * 8 + n];
    out[b * 8 + n] = a2;
  }
}

// ---------------------------------------------------------------------------
extern "C" void kernel_launch(void* const* d_in, const int* in_sizes, int n_in,
                              void* d_out, int out_size, void* d_ws,
                              size_t ws_size, hipStream_t stream) {
  (void)in_sizes; (void)n_in; (void)out_size; (void)ws_size;
  const float* text = (const float*)d_in[0];
  const float* vis  = (const float*)d_in[1];
  const float* aud  = (const float*)d_in[2];
  const float* fc1W = (const float*)d_in[3];
  const float* fc1b = (const float*)d_in[4];
  const float* fc2W = (const float*)d_in[5];
  const float* fc2b = (const float*)d_in[6];
  const float* fc3W = (const float*)d_in[7];
  const float* fc3b = (const float*)d_in[8];
  const float* Wq = (const float*)d_in[9];
  const float* bq = (const float*)d_in[10];
  const float* Wk = (const float*)d_in[11];
  const float* bk = (const float*)d_in[12];
  const float* Wv = (const float*)d_in[13];
  const float* bv = (const float*)d_in[14];
  const float* Wd = (const float*)d_in[15];
  const float* bd = (const float*)d_in[16];
  const float* lng = (const float*)d_in[17];
  const float* lnb = (const float*)d_in[18];
  const float* gWih = (const float*)d_in[19];
  const float* gWhh = (const float*)d_in[20];
  const float* gbih = (const float*)d_in[21];
  const float* gbhh = (const float*)d_in[22];
  const float* fW1 = (const float*)d_in[23];
  const float* fb1 = (const float*)d_in[24];
  const float* bng = (const float*)d_in[25];
  const float* bnb = (const float*)d_in[26];
  const float* fW2 = (const float*)d_in[27];
  const float* fb2 = (const float*)d_in[28];
  float* out = (float*)d_out;

  unsigned short* WSB = (unsigned short*)d_ws;
  unsigned short* T   = WSB;
  unsigned short* Vv  = WSB + SZ;
  unsigned short* Aa  = WSB + 2 * SZ;
  unsigned short* QKV = WSB + 3 * SZ;
  unsigned short* CTX = WSB + 12 * SZ;
  unsigned short* GXR = WSB;              // slices 0..17 ([6][32768][384])
  unsigned short* GRUIN = WSB + 18 * SZ;  // slices 18..20
  unsigned short* WB  = WSB + 21 * SZ;
  float* VS = (float*)(WSB + 21 * SZ + 1048576);
  float* HS = VS + 6 * 64 * 128;
  float* gbihs = HS + 6 * 64 * 128;       // 2304 floats
  float* bqs = gbihs + 6 * 384;           // 768 floats

  prep_kernel<<<dim3(1024), dim3(256), 0, stream>>>(
      fc1W, fc2W, fc3W, Wq, Wk, Wv, Wd, gWih, gWhh, gbih, gbhh, bq, WB,
      gbihs, bqs);
  hipMemsetAsync(VS, 0, 6 * 64 * 128 * sizeof(float), stream);

  {
    GArgs ga{};
    ga.gw = 1;
    ga.g[0] = {text, WB + WB_P1, fc1b, T, 300, 320, 1, 1, 128};  // abf=1: aligned
    ga.g[1] = {vis,  WB + WB_P2, fc2b, Vv, 35, 64, 0, 1, 128};
    ga.g[2] = {aud,  WB + WB_P3, fc3b, Aa, 74, 96, 0, 1, 128};
    gemm_proj<<<dim3(256, 1, 3), dim3(256), 0, stream>>>(ga);
  }

  const int qsel[6] = {0, 2, 0, 1, 1, 2};
  const int ksel[6] = {2, 0, 1, 0, 2, 1};
  unsigned short* proj[3] = {T, Vv, Aa};

  for (int phase = 0; phase < 2; ++phase) {
    // Grouped QKV: 3 A-groups (one per proj source), 2-4 W-tiles each.
    GArgs ga{};
    ga.gw = 4;
    int cnt[3] = {0, 0, 0};
    for (int ul = 0; ul < 3; ++ul) {
      int u = phase * 3 + ul;
      for (int op = 0; op < 3; ++op) {
        int a = (op == 0) ? qsel[u] : ksel[u];
        int z = ul * 3 + op;
        const float* bias = (op == 0) ? (bqs + u * 128)
                          : (op == 1) ? (bk + u * 128) : (bv + u * 128);
        float* vsum = (op == 2) ? (VS + (size_t)u * BB * DD) : nullptr;
        ga.g[a * 4 + cnt[a]] = {proj[a],
                                WB + WB_QKVD + op * 98304 + u * 16384, bias,
                                QKV + (size_t)z * SZ, 128, 128, 0, 1, 128,
                                vsum};
        cnt[a]++;
      }
    }
    for (int a = 0; a < 3; ++a) ga.g[a * 4].abf = cnt[a];
    gemm_k128g<<<dim3(256, 1, 3), dim3(256), 0, stream>>>(ga);
    attn2<<<dim3(2, 128, 3), dim3(256), 0, stream>>>(
        QKV, VS + phase * 3 * BB * DD, CTX + (size_t)phase * 3 * SZ);
  }

  // Fused dual-unit dense+LN: GRUIN[g] = 0.5*LN(CTX_u1@Wd+bd) +
  // 0.5*LN(CTX_u2@Wd+bd), single launch (grid 256x3), pairs gw=2.
  {
    const int u1t[3] = {1, 2, 0};
    const int u2t[3] = {3, 5, 4};
    GArgs ga{};
    ga.gw = 2;
    for (int g = 0; g < 3; ++g) {
      int u1 = u1t[g], u2 = u2t[g];
      ga.g[g * 2 + 0] = {CTX + (size_t)u1 * SZ,
                         WB + WB_QKVD + 3 * 98304 + u1 * 16384,
                         bd + u1 * 128, GRUIN + (size_t)g * SZ, 128, 128, 2, 0,
                         128, nullptr, lng + u1 * 128, lnb + u1 * 128};
      ga.g[g * 2 + 1] = {CTX + (size_t)u2 * SZ,
                         WB + WB_QKVD + 3 * 98304 + u2 * 16384,
                         bd + u2 * 128, nullptr, 128, 128, 0, 0,
                         128, nullptr, lng + u2 * 128, lnb + u2 * 128};
    }
    gemm_dln2<<<dim3(256, 1, 3), dim3(256), 0, stream>>>(ga);
  }

  // gx = GRUIN[g] @ Wih[rec]^T + gbihs[rec] -> row-major GXR (coalesced).
  // Grouped: 3 A-groups (one per GRUIN slice) x 6 W-tiles (2 rec x 3 ny).
  {
    GArgs ga{};
    ga.gw = 6;
    for (int g = 0; g < 3; ++g) {
      for (int i = 0; i < 6; ++i) {
        int dr = i / 3, ny = i % 3, r6 = g * 2 + dr;
        ga.g[g * 6 + i] = {GRUIN + (size_t)g * SZ,
                           WB + WB_WIH + r6 * 49152 + ny * 16384,
                           gbihs + r6 * 384 + ny * 128,
                           GXR + (size_t)r6 * 12582912 + ny * 128,
                           128, 128, (i == 0) ? 6 : 0, 1, 384, nullptr};
      }
    }
    gemm_k128g<<<dim3(256, 1, 3), dim3(256), 0, stream>>>(ga);
  }

  gru8<<<dim3(16, 6), dim3(512), 0, stream>>>(GXR, WB, gbhh, HS);
  head_kernel<<<dim3(BB), dim3(256), 0, stream>>>(HS, fW1, fb1, bng, bnb, fW2, fb2, out);
}